// Round 8
// baseline (188.320 us; speedup 1.0000x reference)
//
#include <hip/hip_runtime.h>

#define BATCH 16
#define HI 384
#define WI 384
#define CH 32
#define OUT_H 384
#define OUT_W 384
#define HW (HI * WI)
#define NBLK 128                       // partial-sum blocks per batch image
#define TILE_W 8
#define TILE_H 4
#define REPS 4                         // vertical tiles per block (8x16 supertile)
#define STILE_H (TILE_H * REPS)        // 16
#define TILES_X (OUT_W / TILE_W)       // 48
#define STILES_Y (OUT_H / STILE_H)     // 24
#define STILES_PER_IMG (TILES_X * STILES_Y)   // 1152
#define SAMP_BLOCKS (BATCH * STILES_PER_IMG)  // 18432, divisible by 8

typedef float f32x4 __attribute__((ext_vector_type(4)));

// ---------------------------------------------------------------------------
// Kernel 1: per-(batch, slice) partial sums (mean pass). No atomics,
// deterministic; 1KB contiguous per wave-iteration; 8 blocks/CU.
// Normal (cache-allocating) loads on purpose: leaves X warm in L3 for the
// gather phase (round-5 counters: gather HBM fetch only ~141MB).
// ---------------------------------------------------------------------------
__global__ __launch_bounds__(256) void k_partial_sums(
    const float* __restrict__ X, float* __restrict__ partials) {
  const int blk = blockIdx.x;  // [0, BATCH*NBLK)
  const int b = blk / NBLK;
  const int sub = blk % NBLK;
  const int t = threadIdx.x;
  const int c4 = t & 7;
  const int poff = t >> 3;     // 0..31
  const int ppb = HW / NBLK;   // 1152
  const int p0 = sub * ppb;

  const f32x4* base = (const f32x4*)(X + (size_t)b * HW * CH);
  f32x4 acc = {0.f, 0.f, 0.f, 0.f};
#pragma unroll 4
  for (int p = p0 + poff; p < p0 + ppb; p += 32) {
    acc += base[(size_t)p * 8 + c4];
  }

  __shared__ f32x4 sh[256];
  sh[t] = acc;
  __syncthreads();
  if (t < 8) {
    f32x4 s = {0.f, 0.f, 0.f, 0.f};
    for (int i = 0; i < 32; ++i) s += sh[i * 8 + t];
    ((f32x4*)(partials + (size_t)blk * CH))[t] = s;
  }
}

// ---------------------------------------------------------------------------
// Kernel 2: reduce partials -> feat [B,32], then theta = feat@W + b.
// ---------------------------------------------------------------------------
__global__ __launch_bounds__(512) void k_theta(
    const float* __restrict__ partials, const float* __restrict__ Wl,
    const float* __restrict__ bl, float* __restrict__ theta) {
  __shared__ float feat[BATCH * CH];  // 512
  const int t = threadIdx.x;
  {
    const int b = t >> 5, c = t & 31;
    float s = 0.f;
#pragma unroll 8
    for (int i = 0; i < NBLK; ++i)
      s += partials[((size_t)b * NBLK + i) * CH + c];
    feat[t] = s * (1.0f / (float)HW);
  }
  __syncthreads();
  if (t < BATCH * 6) {
    const int b = t / 6, j = t % 6;
    float s = bl[j];
    for (int c = 0; c < CH; ++c) s += feat[b * CH + c] * Wl[c * 6 + j];
    theta[t] = s;
  }
}

// ---------------------------------------------------------------------------
// Kernel 3: affine grid + bilinear sample. Block = 8x16 output supertile
// processed as 4 reps of an 8x4 tile (wave w = tile row w), 8 threads/pixel.
// 2-deep software pipeline: rep r+1's four 1KB-per-wave gather loads are
// issued BEFORE consuming rep r (8 outstanding loads/wave, above the
// bandwidth-delay product), attacking one-shot wave-churn overhead (4x fewer
// waves than round 7) without round-5's depth-1 latency collapse. Vertical
// tap reuse across reps (rep r's y1 rows == rep r+1's y0 rows) now lands in
// L1 within the same wave.
// Column-major supertile order + bijective XCD swizzle: consecutive blocks
// on one XCD are vertically adjacent -> row reuse stays in that XCD's L2.
// Math matches reference exactly: floor -> weights from unclipped fracs,
// indices clipped to [0, 383].
// ---------------------------------------------------------------------------
struct Taps {
  f32x4 g00, g01, g10, g11;
  float w00, w01, w10, w11;
  size_t n;  // output f32x4 slot (pixel*8 + c4)
};

__device__ __forceinline__ Taps load_taps(const f32x4* img, const float* th,
                                          int ox, int oy, int c4, size_t obase) {
  Taps tp;
  const float gx = fmaf((float)ox, 2.0f / (float)(OUT_W - 1), -1.0f);
  const float gy = fmaf((float)oy, 2.0f / (float)(OUT_H - 1), -1.0f);
  const float sx = th[0] * gx + th[1] * gy + th[2];
  const float sy = th[3] * gx + th[4] * gy + th[5];
  const float x = (sx + 1.0f) * 0.5f * (float)(WI - 1);
  const float y = (sy + 1.0f) * 0.5f * (float)(HI - 1);

  const float x0f = floorf(x), y0f = floorf(y);
  const float wx1 = x - x0f, wx0 = 1.0f - wx1;
  const float wy1 = y - y0f, wy0 = 1.0f - wy1;
  const int x0 = min(max((int)x0f, 0), WI - 1);
  const int x1 = min(max((int)x0f + 1, 0), WI - 1);
  const int y0 = min(max((int)y0f, 0), HI - 1);
  const int y1 = min(max((int)y0f + 1, 0), HI - 1);

  tp.g00 = img[((size_t)y0 * WI + x0) * 8 + c4];
  tp.g01 = img[((size_t)y0 * WI + x1) * 8 + c4];
  tp.g10 = img[((size_t)y1 * WI + x0) * 8 + c4];
  tp.g11 = img[((size_t)y1 * WI + x1) * 8 + c4];
  tp.w00 = wy0 * wx0; tp.w01 = wy0 * wx1;
  tp.w10 = wy1 * wx0; tp.w11 = wy1 * wx1;
  tp.n = (obase + (size_t)oy * OUT_W + ox) * 8 + c4;
  return tp;
}

__device__ __forceinline__ void consume_taps(const Taps& tp, float* out) {
  const f32x4 r = tp.g00 * tp.w00 + tp.g01 * tp.w01 + tp.g10 * tp.w10 +
                  tp.g11 * tp.w11;
  __builtin_nontemporal_store(r, (f32x4*)out + tp.n);
}

__global__ __launch_bounds__(256) void k_sample(
    const float* __restrict__ X, const float* __restrict__ theta,
    float* __restrict__ out) {
  // bijective XCD swizzle (gridDim.x = 18432, divisible by 8)
  const int q = SAMP_BLOCKS >> 3;
  const int bid = blockIdx.x;
  const int blk = (bid & 7) * q + (bid >> 3);

  const int b = blk / STILES_PER_IMG;
  const int r0 = blk % STILES_PER_IMG;
  const int tx = r0 / STILES_Y;  // column-major: consecutive blk -> sty+1
  const int sty = r0 % STILES_Y;

  const int t = threadIdx.x;
  const int c4 = t & 7;
  const int px = t >> 3;   // 0..31
  const int col = px & 7;  // 0..7
  const int row = px >> 3; // 0..3 (wave id)

  const int ox = tx * TILE_W + col;
  const int oy0 = sty * STILE_H + row;

  const float* th = theta + b * 6;
  const f32x4* img = (const f32x4*)(X + (size_t)b * HW * CH);
  const size_t obase = (size_t)b * (OUT_H * OUT_W);

  Taps cur = load_taps(img, th, ox, oy0, c4, obase);
  Taps nxt1 = load_taps(img, th, ox, oy0 + TILE_H, c4, obase);
  consume_taps(cur, out);
  Taps nxt2 = load_taps(img, th, ox, oy0 + 2 * TILE_H, c4, obase);
  consume_taps(nxt1, out);
  Taps nxt3 = load_taps(img, th, ox, oy0 + 3 * TILE_H, c4, obase);
  consume_taps(nxt2, out);
  consume_taps(nxt3, out);
}

extern "C" void kernel_launch(void* const* d_in, const int* in_sizes, int n_in,
                              void* d_out, int out_size, void* d_ws,
                              size_t ws_size, hipStream_t stream) {
  const float* X = (const float*)d_in[0];
  const float* Wl = (const float*)d_in[1];
  const float* bl = (const float*)d_in[2];
  float* out = (float*)d_out;

  float* partials = (float*)d_ws;                       // BATCH*NBLK*CH floats
  float* theta = partials + (size_t)BATCH * NBLK * CH;  // BATCH*6 floats

  k_partial_sums<<<BATCH * NBLK, 256, 0, stream>>>(X, partials);
  k_theta<<<1, 512, 0, stream>>>(partials, Wl, bl, theta);
  k_sample<<<SAMP_BLOCKS, 256, 0, stream>>>(X, theta, out);
}